// Round 6
// baseline (220.699 us; speedup 1.0000x reference)
//
#include <hip/hip_runtime.h>
#include <hip/hip_bf16.h>
#include <cstdint>

#define DEV __device__ __forceinline__

constexpr int B = 64, T = 1024, N = 512, D = 64, K = 80;

typedef __attribute__((ext_vector_type(8))) short bf16x8;
typedef __attribute__((ext_vector_type(4))) float f32x4;

DEV float fast_tanh(float x) {
    x = fminf(fmaxf(x, -15.f), 15.f);
    float e = __expf(2.f * x);
    return (e - 1.f) / (e + 1.f);
}

DEV unsigned short f2bf(float f) {
    unsigned int u = __float_as_uint(f);
    unsigned int r = (u + 0x7fffu + ((u >> 16) & 1u)) >> 16;
    return (unsigned short)r;
}
DEV float bf2f(unsigned short s) {
    return __uint_as_float(((unsigned int)s) << 16);
}

// Fragment-native tiled layout for all bf16 intermediate buffers.
// off(row,col) = ((row/16)*(S/8) + col/8)*128 + (row%16)*8 + (col%8)
// => a wave's MFMA fragment load (rows base+lr, cols c0+lg*8) is a single
//    contiguous 1KB segment. S8 = columns/8.
DEV size_t tix(size_t row, int col, int S8) {
    return (((row >> 4) * S8 + (size_t)(col >> 3)) << 7) + ((row & 15) << 3) + (col & 7);
}

#define MFMA(a, b, c) __builtin_amdgcn_mfma_f32_16x16x32_bf16((a), (b), (c), 0, 0, 0)

// ---------------------------------------------------------------------------
// Kernel A: M[b,t,:] = review[b,t,:] @ Wl, written as bf16 hi/lo pair (tiled)
__global__ __launch_bounds__(256) void k_matWl(const float* __restrict__ review,
                                               const float* __restrict__ Wl,
                                               unsigned short* __restrict__ Mhi,
                                               unsigned short* __restrict__ Mlo) {
    __shared__ float Wls[64][64];
    __shared__ float Rs[4][64];
    int tid = threadIdx.x;
    size_t base = (size_t)blockIdx.x * 256;
#pragma unroll
    for (int i = 0; i < 16; i++) { int e = tid + i * 256; Wls[e >> 6][e & 63] = Wl[e]; }
    Rs[tid >> 6][tid & 63] = review[base + tid];
    __syncthreads();
    int r = tid >> 6, c = tid & 63;
    float acc = 0.f;
#pragma unroll
    for (int d = 0; d < 64; d++) acc += Rs[r][d] * Wls[d][c];
    unsigned short h = f2bf(acc);
    size_t o = tix((size_t)blockIdx.x * 4 + r, c, 8);
    Mhi[o] = h;
    Mlo[o] = f2bf(acc - bf2f(h));
}

// ---------------------------------------------------------------------------
// Splitter: f32 -> bf16 hi/lo, elementwise, tiled-layout output (for post)
__global__ __launch_bounds__(256) void k_split(const float* __restrict__ X,
                                               unsigned short* __restrict__ Xhi,
                                               unsigned short* __restrict__ Xlo,
                                               int n4) {
    int i = blockIdx.x * 256 + threadIdx.x;
    if (i >= n4) return;
    float4 v = *reinterpret_cast<const float4*>(X + (size_t)i * 4);
    ushort4 h, lo;
    h.x = f2bf(v.x); lo.x = f2bf(v.x - bf2f(h.x));
    h.y = f2bf(v.y); lo.y = f2bf(v.y - bf2f(h.y));
    h.z = f2bf(v.z); lo.z = f2bf(v.z - bf2f(h.z));
    h.w = f2bf(v.w); lo.w = f2bf(v.w - bf2f(h.w));
    size_t o = tix((size_t)(i >> 4), (i & 15) * 4, 8);   // row = i*4/64, col = (i*4)%64
    *reinterpret_cast<ushort4*>(Xhi + o) = h;
    *reinterpret_cast<ushort4*>(Xlo + o) = lo;
}

// ---------------------------------------------------------------------------
// Kernel B: proj[b,k,s] = sum_d W[k,d] * X[b,s,d], bf16 hi/lo pair, tiled
__global__ __launch_bounds__(256) void k_proj(const float* __restrict__ W,
                                              const float* __restrict__ X,
                                              unsigned short* __restrict__ Phi,
                                              unsigned short* __restrict__ Plo, int S) {
    __shared__ float Ws[80][64];
    __shared__ float Xs[64][65];
    int tid = threadIdx.x, tx = tid & 63, ty = tid >> 6;
    int b = blockIdx.y, s0 = blockIdx.x * 64;
#pragma unroll
    for (int i = 0; i < 20; i++) { int e = tid + i * 256; Ws[e >> 6][e & 63] = W[e]; }
    const float* Xp = X + ((size_t)b * S + s0) * 64;
#pragma unroll
    for (int i = 0; i < 16; i++) { int e = tid + i * 256; Xs[e >> 6][e & 63] = Xp[e]; }
    __syncthreads();
    float acc[20];
#pragma unroll
    for (int kk = 0; kk < 20; kk++) acc[kk] = 0.f;
    for (int d = 0; d < 64; d += 4) {
        float x0 = Xs[tx][d], x1 = Xs[tx][d + 1], x2 = Xs[tx][d + 2], x3 = Xs[tx][d + 3];
#pragma unroll
        for (int kk = 0; kk < 20; kk++) {
            const float4 w = *reinterpret_cast<const float4*>(&Ws[ty * 20 + kk][d]);
            acc[kk] += w.x * x0 + w.y * x1 + w.z * x2 + w.w * x3;
        }
    }
    int S8 = S >> 3;
#pragma unroll
    for (int kk = 0; kk < 20; kk++) {
        size_t idx = tix((size_t)b * K + ty * 20 + kk, s0 + tx, S8);
        float v = acc[kk];
        unsigned short h = f2bf(v);
        Phi[idx] = h;
        Plo[idx] = f2bf(v - bf2f(h));
    }
}

// ---------------------------------------------------------------------------
// Fused HP v6: 256 threads = 4 waves. wg=wv&1 owns n-rows [32wg,32wg+32) of
// the 64-row chunk; tg=wv>>1 owns half the t-range (it<8, t0=(tg+2*it)*64).
// Immediate tanh->LDS write keeps accumulator live range at one f32x4.
// 256-thread block makes __launch_bounds__(256,4) an unambiguous 128-VGPR cap
// (v4/v5 at 512 threads compiled to the 64-VGPR tier and spilled 13-44 MB).
// Cross-tg reduction: single 2-way staged round in LDS (Lt dead by then).
__global__ __launch_bounds__(256, 4) void k_hp_fused(
    const unsigned short* __restrict__ Mhi, const unsigned short* __restrict__ Mlo,
    const unsigned short* __restrict__ PsH, const unsigned short* __restrict__ PsL,
    const unsigned short* __restrict__ Rhi, const unsigned short* __restrict__ Rlo,
    const unsigned short* __restrict__ Phi, const unsigned short* __restrict__ Plo,
    const float* __restrict__ whp, float* __restrict__ logits_p) {
    __shared__ __align__(16) float smem[5120];          // 20,480 B
    typedef unsigned short LtArr[64][72];
    LtArr* Lt = reinterpret_cast<LtArr*>(smem);          // Lt[2][64][72] = 18,432 B
    float* redf = smem;                                  // reduce scratch (after loop)
    int b = blockIdx.x, nc0 = blockIdx.y * 64;
    int tid = threadIdx.x, l = tid & 63, wv = tid >> 6;
    int wg = wv & 1, tg = wv >> 1;
    int lr = l & 15, lg = l >> 4;

    // Preload A-operand (post rows for this wave's two n-slices): loop-invariant.
    bf16x8 pah[2][2], pal[2][2];
#pragma unroll
    for (int s = 0; s < 2; s++)
#pragma unroll
        for (int c = 0; c < 2; c++) {
            size_t o = tix((size_t)b * N + nc0 + wg * 32 + s * 16 + lr, c * 32 + lg * 8, 8);
            pah[s][c] = *reinterpret_cast<const bf16x8*>(PsH + o);
            pal[s][c] = *reinterpret_cast<const bf16x8*>(PsL + o);
        }

    f32x4 hp[2][5];
#pragma unroll
    for (int s = 0; s < 2; s++)
#pragma unroll
        for (int f = 0; f < 5; f++) hp[s][f] = (f32x4){0.f, 0.f, 0.f, 0.f};

    for (int it = 0; it < 8; it++) {
        int t0 = (tg + it * 2) * 64;
        // phase 1 (swapped operands): per tf, both s-slices, tanh straight to LDS.
#pragma unroll
        for (int tf = 0; tf < 4; tf++) {
            size_t mrow = (size_t)b * T + t0 + tf * 16 + lr;
            size_t m0 = tix(mrow, lg * 8, 8), m1 = tix(mrow, 32 + lg * 8, 8);
            bf16x8 mh0 = *reinterpret_cast<const bf16x8*>(Mhi + m0);
            bf16x8 mh1 = *reinterpret_cast<const bf16x8*>(Mhi + m1);
            bf16x8 ml0 = *reinterpret_cast<const bf16x8*>(Mlo + m0);
            bf16x8 ml1 = *reinterpret_cast<const bf16x8*>(Mlo + m1);
#pragma unroll
            for (int s = 0; s < 2; s++) {
                f32x4 a = (f32x4){0.f, 0.f, 0.f, 0.f};
                a = MFMA(pah[s][0], mh0, a);
                a = MFMA(pah[s][0], ml0, a);
                a = MFMA(pal[s][0], mh0, a);
                a = MFMA(pah[s][1], mh1, a);
                a = MFMA(pah[s][1], ml1, a);
                a = MFMA(pal[s][1], mh1, a);
#pragma unroll
                for (int r = 0; r < 4; r++)
                    Lt[tg][wg * 32 + s * 16 + lg * 4 + r][tf * 16 + lr] =
                        f2bf(fast_tanh(a[r]));
            }
        }
        bf16x8 bt0[2], bt1[2];
#pragma unroll
        for (int s = 0; s < 2; s++) {
            bt0[s] = *reinterpret_cast<const bf16x8*>(&Lt[tg][wg * 32 + s * 16 + lr][lg * 8]);
            bt1[s] = *reinterpret_cast<const bf16x8*>(&Lt[tg][wg * 32 + s * 16 + lr][32 + lg * 8]);
        }
        // phase 2: hp[s][k] += Rr[k, t-tile] @ Lt[slice s]; Rr loads shared across s
#pragma unroll
        for (int kf = 0; kf < 5; kf++) {
            size_t krow = (size_t)b * K + kf * 16 + lr;
            size_t r0 = tix(krow, t0 + lg * 8, 128), r1 = tix(krow, t0 + 32 + lg * 8, 128);
            bf16x8 rh0 = *reinterpret_cast<const bf16x8*>(Rhi + r0);
            bf16x8 rh1 = *reinterpret_cast<const bf16x8*>(Rhi + r1);
            bf16x8 rl0 = *reinterpret_cast<const bf16x8*>(Rlo + r0);
            bf16x8 rl1 = *reinterpret_cast<const bf16x8*>(Rlo + r1);
#pragma unroll
            for (int s = 0; s < 2; s++) {
                hp[s][kf] = MFMA(rh0, bt0[s], hp[s][kf]);
                hp[s][kf] = MFMA(rl0, bt0[s], hp[s][kf]);
                hp[s][kf] = MFMA(rh1, bt1[s], hp[s][kf]);
                hp[s][kf] = MFMA(rl1, bt1[s], hp[s][kf]);
            }
        }
    }

    // 2-way cross-tg reduction: tg=1 dumps all 10 f32x4, tg=0 accumulates.
    __syncthreads();                            // all Lt reads done
    if (tg == 1) {
#pragma unroll
        for (int s = 0; s < 2; s++)
#pragma unroll
            for (int kf = 0; kf < 5; kf++) {
                int p = s * 5 + kf;
                *reinterpret_cast<f32x4*>(&redf[p * 512 + (wg * 64 + l) * 4]) = hp[s][kf];
            }
    }
    __syncthreads();
    if (tg == 0) {
#pragma unroll
        for (int s = 0; s < 2; s++)
#pragma unroll
            for (int kf = 0; kf < 5; kf++) {
                int p = s * 5 + kf;
                hp[s][kf] += *reinterpret_cast<f32x4*>(&redf[p * 512 + (wg * 64 + l) * 4]);
            }
        // epilogue
#pragma unroll
        for (int s = 0; s < 2; s++) {
            int n = nc0 + wg * 32 + s * 16 + lr;
            float partial = 0.f;
#pragma unroll
            for (int kf = 0; kf < 5; kf++)
#pragma unroll
                for (int r = 0; r < 4; r++) {
                    int k = kf * 16 + lg * 4 + r;
                    size_t idx = tix((size_t)b * K + k, n, 64);
                    float pp = bf2f(Phi[idx]) + bf2f(Plo[idx]);
                    partial += whp[k] * fast_tanh(pp + hp[s][kf][r]);
                }
            partial += __shfl_xor(partial, 16);
            partial += __shfl_xor(partial, 32);
            if (lg == 0) logits_p[(size_t)b * N + n] = partial;
        }
    }
}

// ---------------------------------------------------------------------------
// Fused HR v6: 256 threads = 4 waves. wg owns t-rows [32wg,32wg+32); ng=wv>>1
// owns half the n-range (it<4, n0=(ng+2*it)*64). Same no-spill structure.
__global__ __launch_bounds__(256, 4) void k_hr_fused(
    const unsigned short* __restrict__ Mhi, const unsigned short* __restrict__ Mlo,
    const unsigned short* __restrict__ PsH, const unsigned short* __restrict__ PsL,
    const unsigned short* __restrict__ Phi, const unsigned short* __restrict__ Plo,
    const unsigned short* __restrict__ Rhi, const unsigned short* __restrict__ Rlo,
    const float* __restrict__ whr, float* __restrict__ logits_r) {
    __shared__ __align__(16) float smem[5120];
    typedef unsigned short LdArr[64][72];
    LdArr* Ld = reinterpret_cast<LdArr*>(smem);
    float* redf = smem;
    int b = blockIdx.x, tc0 = blockIdx.y * 64;
    int tid = threadIdx.x, l = tid & 63, wv = tid >> 6;
    int wg = wv & 1, ng = wv >> 1;
    int lr = l & 15, lg = l >> 4;

    // Preload A (M) fragments for this wave's two t-slices: loop-invariant.
    bf16x8 mh0[2], mh1[2], ml0[2], ml1[2];
#pragma unroll
    for (int s = 0; s < 2; s++) {
        size_t mrow = (size_t)b * T + tc0 + wg * 32 + s * 16 + lr;
        size_t m0 = tix(mrow, lg * 8, 8), m1 = tix(mrow, 32 + lg * 8, 8);
        mh0[s] = *reinterpret_cast<const bf16x8*>(Mhi + m0);
        mh1[s] = *reinterpret_cast<const bf16x8*>(Mhi + m1);
        ml0[s] = *reinterpret_cast<const bf16x8*>(Mlo + m0);
        ml1[s] = *reinterpret_cast<const bf16x8*>(Mlo + m1);
    }

    f32x4 hr[2][5];
#pragma unroll
    for (int s = 0; s < 2; s++)
#pragma unroll
        for (int f = 0; f < 5; f++) hr[s][f] = (f32x4){0.f, 0.f, 0.f, 0.f};

    for (int it = 0; it < 4; it++) {
        int n0 = (ng + it * 2) * 64;
#pragma unroll
        for (int nf = 0; nf < 4; nf++) {
            size_t prow = (size_t)b * N + n0 + nf * 16 + lr;
            size_t p0 = tix(prow, lg * 8, 8), p1 = tix(prow, 32 + lg * 8, 8);
            bf16x8 ph0 = *reinterpret_cast<const bf16x8*>(PsH + p0);
            bf16x8 ph1 = *reinterpret_cast<const bf16x8*>(PsH + p1);
            bf16x8 pl0 = *reinterpret_cast<const bf16x8*>(PsL + p0);
            bf16x8 pl1 = *reinterpret_cast<const bf16x8*>(PsL + p1);
#pragma unroll
            for (int s = 0; s < 2; s++) {
                f32x4 a = (f32x4){0.f, 0.f, 0.f, 0.f};
                a = MFMA(mh0[s], ph0, a);
                a = MFMA(mh0[s], pl0, a);
                a = MFMA(ml0[s], ph0, a);
                a = MFMA(mh1[s], ph1, a);
                a = MFMA(mh1[s], pl1, a);
                a = MFMA(ml1[s], ph1, a);
#pragma unroll
                for (int r = 0; r < 4; r++)
                    Ld[ng][wg * 32 + s * 16 + lg * 4 + r][nf * 16 + lr] =
                        f2bf(fast_tanh(a[r]));
            }
        }
        bf16x8 bt0[2], bt1[2];
#pragma unroll
        for (int s = 0; s < 2; s++) {
            bt0[s] = *reinterpret_cast<const bf16x8*>(&Ld[ng][wg * 32 + s * 16 + lr][lg * 8]);
            bt1[s] = *reinterpret_cast<const bf16x8*>(&Ld[ng][wg * 32 + s * 16 + lr][32 + lg * 8]);
        }
        // phase 2: hr[s][k] += Pp[k, n-tile] @ L[slice s]; Pp loads shared across s
#pragma unroll
        for (int kf = 0; kf < 5; kf++) {
            size_t krow = (size_t)b * K + kf * 16 + lr;
            size_t q0 = tix(krow, n0 + lg * 8, 64), q1 = tix(krow, n0 + 32 + lg * 8, 64);
            bf16x8 qh0 = *reinterpret_cast<const bf16x8*>(Phi + q0);
            bf16x8 qh1 = *reinterpret_cast<const bf16x8*>(Phi + q1);
            bf16x8 ql0 = *reinterpret_cast<const bf16x8*>(Plo + q0);
            bf16x8 ql1 = *reinterpret_cast<const bf16x8*>(Plo + q1);
#pragma unroll
            for (int s = 0; s < 2; s++) {
                hr[s][kf] = MFMA(qh0, bt0[s], hr[s][kf]);
                hr[s][kf] = MFMA(ql0, bt0[s], hr[s][kf]);
                hr[s][kf] = MFMA(qh1, bt1[s], hr[s][kf]);
                hr[s][kf] = MFMA(ql1, bt1[s], hr[s][kf]);
            }
        }
    }

    // 2-way cross-ng reduction: ng=1 dumps, ng=0 accumulates + epilogue.
    __syncthreads();
    if (ng == 1) {
#pragma unroll
        for (int s = 0; s < 2; s++)
#pragma unroll
            for (int kf = 0; kf < 5; kf++) {
                int p = s * 5 + kf;
                *reinterpret_cast<f32x4*>(&redf[p * 512 + (wg * 64 + l) * 4]) = hr[s][kf];
            }
    }
    __syncthreads();
    if (ng == 0) {
#pragma unroll
        for (int s = 0; s < 2; s++)
#pragma unroll
            for (int kf = 0; kf < 5; kf++) {
                int p = s * 5 + kf;
                hr[s][kf] += *reinterpret_cast<f32x4*>(&redf[p * 512 + (wg * 64 + l) * 4]);
            }
        // epilogue
#pragma unroll
        for (int s = 0; s < 2; s++) {
            int t = tc0 + wg * 32 + s * 16 + lr;
            float partial = 0.f;
#pragma unroll
            for (int kf = 0; kf < 5; kf++)
#pragma unroll
                for (int r = 0; r < 4; r++) {
                    int k = kf * 16 + lg * 4 + r;
                    size_t idx = tix((size_t)b * K + k, t, 128);
                    float rr = bf2f(Rhi[idx]) + bf2f(Rlo[idx]);
                    partial += whr[k] * fast_tanh(rr + hr[s][kf][r]);
                }
            partial += __shfl_xor(partial, 16);
            partial += __shfl_xor(partial, 32);
            if (lg == 0) logits_r[(size_t)b * T + t] = partial;
        }
    }
}

// ---------------------------------------------------------------------------
// Zero the output buffer (for atomic pooled accumulation). grid = B*128/256.
__global__ __launch_bounds__(256) void k_zero(float* __restrict__ out) {
    out[(size_t)blockIdx.x * 256 + threadIdx.x] = 0.f;
}

// ---------------------------------------------------------------------------
// Kernel F/G: softmax over S, then out[b, off+d] += sum_{s in chunk} sm[s]*X[b,s,d].
__global__ __launch_bounds__(256) void k_softpool(const float* __restrict__ logits,
                                                  const float* __restrict__ X,
                                                  float* __restrict__ out, int S, int off) {
    __shared__ float sm[1024];
    __shared__ float red[256];
    int b = blockIdx.x, tid = threadIdx.x;
    int c0 = blockIdx.y * 128;
    for (int i = tid; i < S; i += 256) sm[i] = logits[(size_t)b * S + i];
    __syncthreads();
    float m = -1e30f;
    for (int i = tid; i < S; i += 256) m = fmaxf(m, sm[i]);
    red[tid] = m;
    __syncthreads();
    for (int s = 128; s > 0; s >>= 1) {
        if (tid < s) red[tid] = fmaxf(red[tid], red[tid + s]);
        __syncthreads();
    }
    float mx = red[0];
    __syncthreads();
    float psum = 0.f;
    for (int i = tid; i < S; i += 256) {
        float e = __expf(sm[i] - mx);
        sm[i] = e;
        psum += e;
    }
    red[tid] = psum;
    __syncthreads();
    for (int s = 128; s > 0; s >>= 1) {
        if (tid < s) red[tid] += red[tid + s];
        __syncthreads();
    }
    float inv = 1.f / red[0];
    __syncthreads();
    int d = tid & 63, g = tid >> 6;
    float acc = 0.f;
    for (int n = c0 + g; n < c0 + 128; n += 4) acc += sm[n] * X[((size_t)b * S + n) * 64 + d];
    red[tid] = acc * inv;
    __syncthreads();
    if (g == 0)
        atomicAdd(&out[(size_t)b * 128 + off + d],
                  red[d] + red[64 + d] + red[128 + d] + red[192 + d]);
}

// ---------------------------------------------------------------------------
extern "C" void kernel_launch(void* const* d_in, const int* in_sizes, int n_in,
                              void* d_out, int out_size, void* d_ws, size_t ws_size,
                              hipStream_t stream) {
    const float* review = (const float*)d_in[0];
    const float* post   = (const float*)d_in[1];
    const float* Wl     = (const float*)d_in[2];
    const float* Wr     = (const float*)d_in[3];
    const float* Wp     = (const float*)d_in[4];
    const float* whr    = (const float*)d_in[5];
    const float* whp    = (const float*)d_in[6];
    float* out = (float*)d_out;

    char* p = (char*)d_ws;
    unsigned short* Mhi = (unsigned short*)p;  p += (size_t)B * T * D * 2;
    unsigned short* Mlo = (unsigned short*)p;  p += (size_t)B * T * D * 2;
    unsigned short* PsH = (unsigned short*)p;  p += (size_t)B * N * D * 2;
    unsigned short* PsL = (unsigned short*)p;  p += (size_t)B * N * D * 2;
    unsigned short* Rhi = (unsigned short*)p;  p += (size_t)B * K * T * 2;
    unsigned short* Rlo = (unsigned short*)p;  p += (size_t)B * K * T * 2;
    unsigned short* Phi = (unsigned short*)p;  p += (size_t)B * K * N * 2;
    unsigned short* Plo = (unsigned short*)p;  p += (size_t)B * K * N * 2;
    float* logits_p = (float*)p;        p += (size_t)B * N * 4;
    float* logits_r = (float*)p;        p += (size_t)B * T * 4;

    k_matWl<<<dim3(B * T / 4), dim3(256), 0, stream>>>(review, Wl, Mhi, Mlo);
    k_split<<<dim3(B * N * D / 4 / 256), dim3(256), 0, stream>>>(post, PsH, PsL, B * N * D / 4);
    k_proj<<<dim3(T / 64, B), dim3(256), 0, stream>>>(Wr, review, Rhi, Rlo, T);
    k_proj<<<dim3(N / 64, B), dim3(256), 0, stream>>>(Wp, post, Phi, Plo, N);
    k_zero<<<dim3(B * 128 / 256), dim3(256), 0, stream>>>(out);
    k_hp_fused<<<dim3(B, N / 64), dim3(256), 0, stream>>>(Mhi, Mlo, PsH, PsL, Rhi, Rlo,
                                                          Phi, Plo, whp, logits_p);
    k_hr_fused<<<dim3(B, T / 64), dim3(256), 0, stream>>>(Mhi, Mlo, PsH, PsL, Phi, Plo,
                                                          Rhi, Rlo, whr, logits_r);
    k_softpool<<<dim3(B, N / 128), dim3(256), 0, stream>>>(logits_p, post, out, N, 0);
    k_softpool<<<dim3(B, T / 128), dim3(256), 0, stream>>>(logits_r, review, out, T, 64);
}

// Round 7
// 200.467 us; speedup vs baseline: 1.1009x; 1.1009x over previous
//
#include <hip/hip_runtime.h>
#include <hip/hip_bf16.h>
#include <cstdint>

#define DEV __device__ __forceinline__

constexpr int B = 64, T = 1024, N = 512, D = 64, K = 80;

typedef __attribute__((ext_vector_type(8))) short bf16x8;
typedef __attribute__((ext_vector_type(4))) float f32x4;

DEV float fast_tanh(float x) {
    x = fminf(fmaxf(x, -15.f), 15.f);
    float e = __expf(2.f * x);
    return (e - 1.f) / (e + 1.f);
}

DEV unsigned short f2bf(float f) {
    unsigned int u = __float_as_uint(f);
    unsigned int r = (u + 0x7fffu + ((u >> 16) & 1u)) >> 16;
    return (unsigned short)r;
}
DEV float bf2f(unsigned short s) {
    return __uint_as_float(((unsigned int)s) << 16);
}

// Fragment-native tiled layout for all bf16 intermediate buffers.
// off(row,col) = ((row/16)*(S/8) + col/8)*128 + (row%16)*8 + (col%8)
// => a wave's MFMA fragment load (rows base+lr, cols c0+lg*8) is a single
//    contiguous 1KB segment. S8 = columns/8.
DEV size_t tix(size_t row, int col, int S8) {
    return (((row >> 4) * S8 + (size_t)(col >> 3)) << 7) + ((row & 15) << 3) + (col & 7);
}

#define MFMA(a, b, c) __builtin_amdgcn_mfma_f32_16x16x32_bf16((a), (b), (c), 0, 0, 0)

// ---------------------------------------------------------------------------
// Kernel A: M[b,t,:] = review[b,t,:] @ Wl, written as bf16 hi/lo pair (tiled)
__global__ __launch_bounds__(256) void k_matWl(const float* __restrict__ review,
                                               const float* __restrict__ Wl,
                                               unsigned short* __restrict__ Mhi,
                                               unsigned short* __restrict__ Mlo) {
    __shared__ float Wls[64][64];
    __shared__ float Rs[4][64];
    int tid = threadIdx.x;
    size_t base = (size_t)blockIdx.x * 256;
#pragma unroll
    for (int i = 0; i < 16; i++) { int e = tid + i * 256; Wls[e >> 6][e & 63] = Wl[e]; }
    Rs[tid >> 6][tid & 63] = review[base + tid];
    __syncthreads();
    int r = tid >> 6, c = tid & 63;
    float acc = 0.f;
#pragma unroll
    for (int d = 0; d < 64; d++) acc += Rs[r][d] * Wls[d][c];
    unsigned short h = f2bf(acc);
    size_t o = tix((size_t)blockIdx.x * 4 + r, c, 8);
    Mhi[o] = h;
    Mlo[o] = f2bf(acc - bf2f(h));
}

// ---------------------------------------------------------------------------
// Splitter: f32 -> bf16 hi/lo, elementwise, tiled-layout output (for post)
__global__ __launch_bounds__(256) void k_split(const float* __restrict__ X,
                                               unsigned short* __restrict__ Xhi,
                                               unsigned short* __restrict__ Xlo,
                                               int n4) {
    int i = blockIdx.x * 256 + threadIdx.x;
    if (i >= n4) return;
    float4 v = *reinterpret_cast<const float4*>(X + (size_t)i * 4);
    ushort4 h, lo;
    h.x = f2bf(v.x); lo.x = f2bf(v.x - bf2f(h.x));
    h.y = f2bf(v.y); lo.y = f2bf(v.y - bf2f(h.y));
    h.z = f2bf(v.z); lo.z = f2bf(v.z - bf2f(h.z));
    h.w = f2bf(v.w); lo.w = f2bf(v.w - bf2f(h.w));
    size_t o = tix((size_t)(i >> 4), (i & 15) * 4, 8);   // row = i*4/64, col = (i*4)%64
    *reinterpret_cast<ushort4*>(Xhi + o) = h;
    *reinterpret_cast<ushort4*>(Xlo + o) = lo;
}

// ---------------------------------------------------------------------------
// Kernel B: proj[b,k,s] = sum_d W[k,d] * X[b,s,d], bf16 hi/lo pair, tiled
__global__ __launch_bounds__(256) void k_proj(const float* __restrict__ W,
                                              const float* __restrict__ X,
                                              unsigned short* __restrict__ Phi,
                                              unsigned short* __restrict__ Plo, int S) {
    __shared__ float Ws[80][64];
    __shared__ float Xs[64][65];
    int tid = threadIdx.x, tx = tid & 63, ty = tid >> 6;
    int b = blockIdx.y, s0 = blockIdx.x * 64;
#pragma unroll
    for (int i = 0; i < 20; i++) { int e = tid + i * 256; Ws[e >> 6][e & 63] = W[e]; }
    const float* Xp = X + ((size_t)b * S + s0) * 64;
#pragma unroll
    for (int i = 0; i < 16; i++) { int e = tid + i * 256; Xs[e >> 6][e & 63] = Xp[e]; }
    __syncthreads();
    float acc[20];
#pragma unroll
    for (int kk = 0; kk < 20; kk++) acc[kk] = 0.f;
    for (int d = 0; d < 64; d += 4) {
        float x0 = Xs[tx][d], x1 = Xs[tx][d + 1], x2 = Xs[tx][d + 2], x3 = Xs[tx][d + 3];
#pragma unroll
        for (int kk = 0; kk < 20; kk++) {
            const float4 w = *reinterpret_cast<const float4*>(&Ws[ty * 20 + kk][d]);
            acc[kk] += w.x * x0 + w.y * x1 + w.z * x2 + w.w * x3;
        }
    }
    int S8 = S >> 3;
#pragma unroll
    for (int kk = 0; kk < 20; kk++) {
        size_t idx = tix((size_t)b * K + ty * 20 + kk, s0 + tx, S8);
        float v = acc[kk];
        unsigned short h = f2bf(v);
        Phi[idx] = h;
        Plo[idx] = f2bf(v - bf2f(h));
    }
}

// ---------------------------------------------------------------------------
// Fused HP v7: identical decomposition to v6 (256 thr: wg=wv&1 owns n-rows,
// tg=wv>>1 owns half the t-range), but with plain __launch_bounds__(256):
// the ",4" min-waves hint in v4-v6 forced the 64-VGPR tier (8 waves/EU
// target) and caused 13-44 MB of scratch spill each round. Without it the
// allocator picks ~100-130 VGPRs (cf. rounds 2-3: 120/88, zero spill) and
// the scheduler can keep the kf-loop's 20 loads in flight (MLP).
__global__ __launch_bounds__(256) void k_hp_fused(
    const unsigned short* __restrict__ Mhi, const unsigned short* __restrict__ Mlo,
    const unsigned short* __restrict__ PsH, const unsigned short* __restrict__ PsL,
    const unsigned short* __restrict__ Rhi, const unsigned short* __restrict__ Rlo,
    const unsigned short* __restrict__ Phi, const unsigned short* __restrict__ Plo,
    const float* __restrict__ whp, float* __restrict__ logits_p) {
    __shared__ __align__(16) float smem[5120];          // 20,480 B
    typedef unsigned short LtArr[64][72];
    LtArr* Lt = reinterpret_cast<LtArr*>(smem);          // Lt[2][64][72] = 18,432 B
    float* redf = smem;                                  // reduce scratch (after loop)
    int b = blockIdx.x, nc0 = blockIdx.y * 64;
    int tid = threadIdx.x, l = tid & 63, wv = tid >> 6;
    int wg = wv & 1, tg = wv >> 1;
    int lr = l & 15, lg = l >> 4;

    // Preload A-operand (post rows for this wave's two n-slices): loop-invariant.
    bf16x8 pah[2][2], pal[2][2];
#pragma unroll
    for (int s = 0; s < 2; s++)
#pragma unroll
        for (int c = 0; c < 2; c++) {
            size_t o = tix((size_t)b * N + nc0 + wg * 32 + s * 16 + lr, c * 32 + lg * 8, 8);
            pah[s][c] = *reinterpret_cast<const bf16x8*>(PsH + o);
            pal[s][c] = *reinterpret_cast<const bf16x8*>(PsL + o);
        }

    f32x4 hp[2][5];
#pragma unroll
    for (int s = 0; s < 2; s++)
#pragma unroll
        for (int f = 0; f < 5; f++) hp[s][f] = (f32x4){0.f, 0.f, 0.f, 0.f};

    for (int it = 0; it < 8; it++) {
        int t0 = (tg + it * 2) * 64;
        // phase 1 (swapped operands): per tf, both s-slices, tanh straight to LDS.
#pragma unroll
        for (int tf = 0; tf < 4; tf++) {
            size_t mrow = (size_t)b * T + t0 + tf * 16 + lr;
            size_t m0 = tix(mrow, lg * 8, 8), m1 = tix(mrow, 32 + lg * 8, 8);
            bf16x8 mh0 = *reinterpret_cast<const bf16x8*>(Mhi + m0);
            bf16x8 mh1 = *reinterpret_cast<const bf16x8*>(Mhi + m1);
            bf16x8 ml0 = *reinterpret_cast<const bf16x8*>(Mlo + m0);
            bf16x8 ml1 = *reinterpret_cast<const bf16x8*>(Mlo + m1);
#pragma unroll
            for (int s = 0; s < 2; s++) {
                f32x4 a = (f32x4){0.f, 0.f, 0.f, 0.f};
                a = MFMA(pah[s][0], mh0, a);
                a = MFMA(pah[s][0], ml0, a);
                a = MFMA(pal[s][0], mh0, a);
                a = MFMA(pah[s][1], mh1, a);
                a = MFMA(pah[s][1], ml1, a);
                a = MFMA(pal[s][1], mh1, a);
#pragma unroll
                for (int r = 0; r < 4; r++)
                    Lt[tg][wg * 32 + s * 16 + lg * 4 + r][tf * 16 + lr] =
                        f2bf(fast_tanh(a[r]));
            }
        }
        bf16x8 bt0[2], bt1[2];
#pragma unroll
        for (int s = 0; s < 2; s++) {
            bt0[s] = *reinterpret_cast<const bf16x8*>(&Lt[tg][wg * 32 + s * 16 + lr][lg * 8]);
            bt1[s] = *reinterpret_cast<const bf16x8*>(&Lt[tg][wg * 32 + s * 16 + lr][32 + lg * 8]);
        }
        // phase 2: hp[s][k] += Rr[k, t-tile] @ Lt[slice s]; Rr loads shared across s
#pragma unroll
        for (int kf = 0; kf < 5; kf++) {
            size_t krow = (size_t)b * K + kf * 16 + lr;
            size_t r0 = tix(krow, t0 + lg * 8, 128), r1 = tix(krow, t0 + 32 + lg * 8, 128);
            bf16x8 rh0 = *reinterpret_cast<const bf16x8*>(Rhi + r0);
            bf16x8 rh1 = *reinterpret_cast<const bf16x8*>(Rhi + r1);
            bf16x8 rl0 = *reinterpret_cast<const bf16x8*>(Rlo + r0);
            bf16x8 rl1 = *reinterpret_cast<const bf16x8*>(Rlo + r1);
#pragma unroll
            for (int s = 0; s < 2; s++) {
                hp[s][kf] = MFMA(rh0, bt0[s], hp[s][kf]);
                hp[s][kf] = MFMA(rl0, bt0[s], hp[s][kf]);
                hp[s][kf] = MFMA(rh1, bt1[s], hp[s][kf]);
                hp[s][kf] = MFMA(rl1, bt1[s], hp[s][kf]);
            }
        }
    }

    // 2-way cross-tg reduction: tg=1 dumps all 10 f32x4, tg=0 accumulates.
    __syncthreads();                            // all Lt reads done
    if (tg == 1) {
#pragma unroll
        for (int s = 0; s < 2; s++)
#pragma unroll
            for (int kf = 0; kf < 5; kf++) {
                int p = s * 5 + kf;
                *reinterpret_cast<f32x4*>(&redf[p * 512 + (wg * 64 + l) * 4]) = hp[s][kf];
            }
    }
    __syncthreads();
    if (tg == 0) {
#pragma unroll
        for (int s = 0; s < 2; s++)
#pragma unroll
            for (int kf = 0; kf < 5; kf++) {
                int p = s * 5 + kf;
                hp[s][kf] += *reinterpret_cast<f32x4*>(&redf[p * 512 + (wg * 64 + l) * 4]);
            }
        // epilogue
#pragma unroll
        for (int s = 0; s < 2; s++) {
            int n = nc0 + wg * 32 + s * 16 + lr;
            float partial = 0.f;
#pragma unroll
            for (int kf = 0; kf < 5; kf++)
#pragma unroll
                for (int r = 0; r < 4; r++) {
                    int k = kf * 16 + lg * 4 + r;
                    size_t idx = tix((size_t)b * K + k, n, 64);
                    float pp = bf2f(Phi[idx]) + bf2f(Plo[idx]);
                    partial += whp[k] * fast_tanh(pp + hp[s][kf][r]);
                }
            partial += __shfl_xor(partial, 16);
            partial += __shfl_xor(partial, 32);
            if (lg == 0) logits_p[(size_t)b * N + n] = partial;
        }
    }
}

// ---------------------------------------------------------------------------
// Fused HR v7: identical to v6 but plain __launch_bounds__(256) (see HP v7).
__global__ __launch_bounds__(256) void k_hr_fused(
    const unsigned short* __restrict__ Mhi, const unsigned short* __restrict__ Mlo,
    const unsigned short* __restrict__ PsH, const unsigned short* __restrict__ PsL,
    const unsigned short* __restrict__ Phi, const unsigned short* __restrict__ Plo,
    const unsigned short* __restrict__ Rhi, const unsigned short* __restrict__ Rlo,
    const float* __restrict__ whr, float* __restrict__ logits_r) {
    __shared__ __align__(16) float smem[5120];
    typedef unsigned short LdArr[64][72];
    LdArr* Ld = reinterpret_cast<LdArr*>(smem);
    float* redf = smem;
    int b = blockIdx.x, tc0 = blockIdx.y * 64;
    int tid = threadIdx.x, l = tid & 63, wv = tid >> 6;
    int wg = wv & 1, ng = wv >> 1;
    int lr = l & 15, lg = l >> 4;

    // Preload A (M) fragments for this wave's two t-slices: loop-invariant.
    bf16x8 mh0[2], mh1[2], ml0[2], ml1[2];
#pragma unroll
    for (int s = 0; s < 2; s++) {
        size_t mrow = (size_t)b * T + tc0 + wg * 32 + s * 16 + lr;
        size_t m0 = tix(mrow, lg * 8, 8), m1 = tix(mrow, 32 + lg * 8, 8);
        mh0[s] = *reinterpret_cast<const bf16x8*>(Mhi + m0);
        mh1[s] = *reinterpret_cast<const bf16x8*>(Mhi + m1);
        ml0[s] = *reinterpret_cast<const bf16x8*>(Mlo + m0);
        ml1[s] = *reinterpret_cast<const bf16x8*>(Mlo + m1);
    }

    f32x4 hr[2][5];
#pragma unroll
    for (int s = 0; s < 2; s++)
#pragma unroll
        for (int f = 0; f < 5; f++) hr[s][f] = (f32x4){0.f, 0.f, 0.f, 0.f};

    for (int it = 0; it < 4; it++) {
        int n0 = (ng + it * 2) * 64;
#pragma unroll
        for (int nf = 0; nf < 4; nf++) {
            size_t prow = (size_t)b * N + n0 + nf * 16 + lr;
            size_t p0 = tix(prow, lg * 8, 8), p1 = tix(prow, 32 + lg * 8, 8);
            bf16x8 ph0 = *reinterpret_cast<const bf16x8*>(PsH + p0);
            bf16x8 ph1 = *reinterpret_cast<const bf16x8*>(PsH + p1);
            bf16x8 pl0 = *reinterpret_cast<const bf16x8*>(PsL + p0);
            bf16x8 pl1 = *reinterpret_cast<const bf16x8*>(PsL + p1);
#pragma unroll
            for (int s = 0; s < 2; s++) {
                f32x4 a = (f32x4){0.f, 0.f, 0.f, 0.f};
                a = MFMA(mh0[s], ph0, a);
                a = MFMA(mh0[s], pl0, a);
                a = MFMA(ml0[s], ph0, a);
                a = MFMA(mh1[s], ph1, a);
                a = MFMA(mh1[s], pl1, a);
                a = MFMA(ml1[s], ph1, a);
#pragma unroll
                for (int r = 0; r < 4; r++)
                    Ld[ng][wg * 32 + s * 16 + lg * 4 + r][nf * 16 + lr] =
                        f2bf(fast_tanh(a[r]));
            }
        }
        bf16x8 bt0[2], bt1[2];
#pragma unroll
        for (int s = 0; s < 2; s++) {
            bt0[s] = *reinterpret_cast<const bf16x8*>(&Ld[ng][wg * 32 + s * 16 + lr][lg * 8]);
            bt1[s] = *reinterpret_cast<const bf16x8*>(&Ld[ng][wg * 32 + s * 16 + lr][32 + lg * 8]);
        }
        // phase 2: hr[s][k] += Pp[k, n-tile] @ L[slice s]; Pp loads shared across s
#pragma unroll
        for (int kf = 0; kf < 5; kf++) {
            size_t krow = (size_t)b * K + kf * 16 + lr;
            size_t q0 = tix(krow, n0 + lg * 8, 64), q1 = tix(krow, n0 + 32 + lg * 8, 64);
            bf16x8 qh0 = *reinterpret_cast<const bf16x8*>(Phi + q0);
            bf16x8 qh1 = *reinterpret_cast<const bf16x8*>(Phi + q1);
            bf16x8 ql0 = *reinterpret_cast<const bf16x8*>(Plo + q0);
            bf16x8 ql1 = *reinterpret_cast<const bf16x8*>(Plo + q1);
#pragma unroll
            for (int s = 0; s < 2; s++) {
                hr[s][kf] = MFMA(qh0, bt0[s], hr[s][kf]);
                hr[s][kf] = MFMA(ql0, bt0[s], hr[s][kf]);
                hr[s][kf] = MFMA(qh1, bt1[s], hr[s][kf]);
                hr[s][kf] = MFMA(ql1, bt1[s], hr[s][kf]);
            }
        }
    }

    // 2-way cross-ng reduction: ng=1 dumps, ng=0 accumulates + epilogue.
    __syncthreads();
    if (ng == 1) {
#pragma unroll
        for (int s = 0; s < 2; s++)
#pragma unroll
            for (int kf = 0; kf < 5; kf++) {
                int p = s * 5 + kf;
                *reinterpret_cast<f32x4*>(&redf[p * 512 + (wg * 64 + l) * 4]) = hr[s][kf];
            }
    }
    __syncthreads();
    if (ng == 0) {
#pragma unroll
        for (int s = 0; s < 2; s++)
#pragma unroll
            for (int kf = 0; kf < 5; kf++) {
                int p = s * 5 + kf;
                hr[s][kf] += *reinterpret_cast<f32x4*>(&redf[p * 512 + (wg * 64 + l) * 4]);
            }
        // epilogue
#pragma unroll
        for (int s = 0; s < 2; s++) {
            int t = tc0 + wg * 32 + s * 16 + lr;
            float partial = 0.f;
#pragma unroll
            for (int kf = 0; kf < 5; kf++)
#pragma unroll
                for (int r = 0; r < 4; r++) {
                    int k = kf * 16 + lg * 4 + r;
                    size_t idx = tix((size_t)b * K + k, t, 128);
                    float rr = bf2f(Rhi[idx]) + bf2f(Rlo[idx]);
                    partial += whr[k] * fast_tanh(rr + hr[s][kf][r]);
                }
            partial += __shfl_xor(partial, 16);
            partial += __shfl_xor(partial, 32);
            if (lg == 0) logits_r[(size_t)b * T + t] = partial;
        }
    }
}

// ---------------------------------------------------------------------------
// Zero the output buffer (for atomic pooled accumulation). grid = B*128/256.
__global__ __launch_bounds__(256) void k_zero(float* __restrict__ out) {
    out[(size_t)blockIdx.x * 256 + threadIdx.x] = 0.f;
}

// ---------------------------------------------------------------------------
// Kernel F/G: softmax over S, then out[b, off+d] += sum_{s in chunk} sm[s]*X[b,s,d].
__global__ __launch_bounds__(256) void k_softpool(const float* __restrict__ logits,
                                                  const float* __restrict__ X,
                                                  float* __restrict__ out, int S, int off) {
    __shared__ float sm[1024];
    __shared__ float red[256];
    int b = blockIdx.x, tid = threadIdx.x;
    int c0 = blockIdx.y * 128;
    for (int i = tid; i < S; i += 256) sm[i] = logits[(size_t)b * S + i];
    __syncthreads();
    float m = -1e30f;
    for (int i = tid; i < S; i += 256) m = fmaxf(m, sm[i]);
    red[tid] = m;
    __syncthreads();
    for (int s = 128; s > 0; s >>= 1) {
        if (tid < s) red[tid] = fmaxf(red[tid], red[tid + s]);
        __syncthreads();
    }
    float mx = red[0];
    __syncthreads();
    float psum = 0.f;
    for (int i = tid; i < S; i += 256) {
        float e = __expf(sm[i] - mx);
        sm[i] = e;
        psum += e;
    }
    red[tid] = psum;
    __syncthreads();
    for (int s = 128; s > 0; s >>= 1) {
        if (tid < s) red[tid] += red[tid + s];
        __syncthreads();
    }
    float inv = 1.f / red[0];
    __syncthreads();
    int d = tid & 63, g = tid >> 6;
    float acc = 0.f;
    for (int n = c0 + g; n < c0 + 128; n += 4) acc += sm[n] * X[((size_t)b * S + n) * 64 + d];
    red[tid] = acc * inv;
    __syncthreads();
    if (g == 0)
        atomicAdd(&out[(size_t)b * 128 + off + d],
                  red[d] + red[64 + d] + red[128 + d] + red[192 + d]);
}

// ---------------------------------------------------------------------------
extern "C" void kernel_launch(void* const* d_in, const int* in_sizes, int n_in,
                              void* d_out, int out_size, void* d_ws, size_t ws_size,
                              hipStream_t stream) {
    const float* review = (const float*)d_in[0];
    const float* post   = (const float*)d_in[1];
    const float* Wl     = (const float*)d_in[2];
    const float* Wr     = (const float*)d_in[3];
    const float* Wp     = (const float*)d_in[4];
    const float* whr    = (const float*)d_in[5];
    const float* whp    = (const float*)d_in[6];
    float* out = (float*)d_out;

    char* p = (char*)d_ws;
    unsigned short* Mhi = (unsigned short*)p;  p += (size_t)B * T * D * 2;
    unsigned short* Mlo = (unsigned short*)p;  p += (size_t)B * T * D * 2;
    unsigned short* PsH = (unsigned short*)p;  p += (size_t)B * N * D * 2;
    unsigned short* PsL = (unsigned short*)p;  p += (size_t)B * N * D * 2;
    unsigned short* Rhi = (unsigned short*)p;  p += (size_t)B * K * T * 2;
    unsigned short* Rlo = (unsigned short*)p;  p += (size_t)B * K * T * 2;
    unsigned short* Phi = (unsigned short*)p;  p += (size_t)B * K * N * 2;
    unsigned short* Plo = (unsigned short*)p;  p += (size_t)B * K * N * 2;
    float* logits_p = (float*)p;        p += (size_t)B * N * 4;
    float* logits_r = (float*)p;        p += (size_t)B * T * 4;

    k_matWl<<<dim3(B * T / 4), dim3(256), 0, stream>>>(review, Wl, Mhi, Mlo);
    k_split<<<dim3(B * N * D / 4 / 256), dim3(256), 0, stream>>>(post, PsH, PsL, B * N * D / 4);
    k_proj<<<dim3(T / 64, B), dim3(256), 0, stream>>>(Wr, review, Rhi, Rlo, T);
    k_proj<<<dim3(N / 64, B), dim3(256), 0, stream>>>(Wp, post, Phi, Plo, N);
    k_zero<<<dim3(B * 128 / 256), dim3(256), 0, stream>>>(out);
    k_hp_fused<<<dim3(B, N / 64), dim3(256), 0, stream>>>(Mhi, Mlo, PsH, PsL, Rhi, Rlo,
                                                          Phi, Plo, whp, logits_p);
    k_hr_fused<<<dim3(B, T / 64), dim3(256), 0, stream>>>(Mhi, Mlo, PsH, PsL, Phi, Plo,
                                                          Rhi, Rlo, whr, logits_r);
    k_softpool<<<dim3(B, N / 128), dim3(256), 0, stream>>>(logits_p, post, out, N, 0);
    k_softpool<<<dim3(B, T / 128), dim3(256), 0, stream>>>(logits_r, review, out, T, 64);
}